// Round 2
// baseline (1318.352 us; speedup 1.0000x reference)
//
#include <hip/hip_runtime.h>

typedef __attribute__((ext_vector_type(8))) short bh8;
typedef __attribute__((ext_vector_type(4))) short bh4;
typedef __attribute__((ext_vector_type(4))) float f32x4;

__device__ __forceinline__ short f2bf(float f) {
  union { float f; unsigned u; } a; a.f = f;
  unsigned r = a.u + 0x7FFFu + ((a.u >> 16) & 1u);
  return (short)(r >> 16);
}

// ---------------------------------------------------------------------------
// Prep 1: x[b][c][s] (f32) -> xT[b][s][c] (bf16) for q,k,v. 64x64 tiles.
// grid (16,16,24): z = tensor*8 + b
// ---------------------------------------------------------------------------
__global__ __launch_bounds__(256) void transpose3(
    const float* __restrict__ q, const float* __restrict__ k, const float* __restrict__ v,
    short* __restrict__ qT, short* __restrict__ kT, short* __restrict__ vT) {
  int z = blockIdx.z; int tensor = z >> 3, b = z & 7;
  const float* src = tensor == 0 ? q : (tensor == 1 ? k : v);
  short* dst = tensor == 0 ? qT : (tensor == 1 ? kT : vT);
  src += (size_t)b * 1048576; dst += (size_t)b * 1048576;
  int row0 = blockIdx.y * 64;  // c
  int col0 = blockIdx.x * 64;  // s
  __shared__ short t[64][72];
  int tid = threadIdx.x;
#pragma unroll
  for (int i = 0; i < 2; ++i) {
    int cid = tid + i * 256;
    int r = cid >> 3, co = (cid & 7) * 8;
    const float* p = src + (size_t)(row0 + r) * 1024 + col0 + co;
    float4 f0 = *(const float4*)(p);
    float4 f1 = *(const float4*)(p + 4);
    t[co + 0][r] = f2bf(f0.x); t[co + 1][r] = f2bf(f0.y);
    t[co + 2][r] = f2bf(f0.z); t[co + 3][r] = f2bf(f0.w);
    t[co + 4][r] = f2bf(f1.x); t[co + 5][r] = f2bf(f1.y);
    t[co + 6][r] = f2bf(f1.z); t[co + 7][r] = f2bf(f1.w);
  }
  __syncthreads();
#pragma unroll
  for (int i = 0; i < 2; ++i) {
    int cid = tid + i * 256;
    int sr = cid >> 3, cc = (cid & 7) * 8;
    bh8 val = *(const bh8*)&t[sr][cc];
    *(bh8*)(dst + (size_t)(col0 + sr) * 1024 + row0 + cc) = val;
  }
}

// ---------------------------------------------------------------------------
// Prep 2: Wp[tap][o][c] (bf16) = W[o][c][tap] (f32).  grid (4096, 3)
// ---------------------------------------------------------------------------
__global__ __launch_bounds__(256) void wperm3(
    const float* __restrict__ Wq, const float* __restrict__ Wk, const float* __restrict__ Wv,
    short* __restrict__ WpQ, short* __restrict__ WpK, short* __restrict__ WpV) {
  int z = blockIdx.y;
  const float* W = z == 0 ? Wq : (z == 1 ? Wk : Wv);
  short* Wp = z == 0 ? WpQ : (z == 1 ? WpK : WpV);
  int idx = blockIdx.x * 256 + threadIdx.x;  // (o,c) flat, 0..1M
  const float* wsrc = W + (size_t)idx * 9;
#pragma unroll
  for (int t = 0; t < 9; ++t) Wp[(size_t)t * 1048576 + idx] = f2bf(wsrc[t]);
}

// ---------------------------------------------------------------------------
// Prep 3: Wo f32 -> bf16 flat.  grid (1024)
// ---------------------------------------------------------------------------
__global__ __launch_bounds__(256) void cvt_bf(const float* __restrict__ src,
                                              short* __restrict__ dst) {
  int idx = (blockIdx.x * 256 + threadIdx.x) * 4;
  float4 f = *(const float4*)(src + idx);
  bh4 o; o[0] = f2bf(f.x); o[1] = f2bf(f.y); o[2] = f2bf(f.z); o[3] = f2bf(f.w);
  *(bh4*)(dst + idx) = o;
}

// ---------------------------------------------------------------------------
// Conv3x3 as implicit GEMM, 128x128 tile, K = 9 taps x 1024 c.
// XisA==0 (Q/K convs): out[b][o][s];  XisA==1 (V conv): out[b][sp][o].
// grid (8,8,8) = (mtile, ntile, b)
// ---------------------------------------------------------------------------
template <int XisA>
__global__ __launch_bounds__(256) void conv_gemm(
    const short* __restrict__ Wp, const short* __restrict__ xT,
    short* __restrict__ out, const float* __restrict__ bias) {
  __shared__ short sA[128][32];
  __shared__ short sB[128][32];
  int tid = threadIdx.x, lane = tid & 63, wid = tid >> 6;
  int b = blockIdx.z;
  int mbase = blockIdx.x * 128, nbase = blockIdx.y * 128;
  const short* xb = xT + (size_t)b * 1048576;
  f32x4 acc[4][4] = {};
  int wm = (wid >> 1) * 64, wn = (wid & 1) * 64;
  const bh8 zero8 = {0, 0, 0, 0, 0, 0, 0, 0};
  for (int tap = 0; tap < 9; ++tap) {
    int dy = tap / 3 - 1, dx = tap % 3 - 1;
    const short* wpt = Wp + (size_t)tap * 1048576;
    for (int kt = 0; kt < 1024; kt += 32) {
#pragma unroll
      for (int i = 0; i < 2; ++i) {
        int cid = tid + i * 256;
        int row = cid >> 2, co = (cid & 3) * 8;
        bh8 va, vb;
        if (XisA == 0) {
          va = *(const bh8*)(wpt + (size_t)(mbase + row) * 1024 + kt + co);
          int s = nbase + row, y = s >> 5, x = s & 31;
          int yy = y + dy, xx = x + dx;
          vb = zero8;
          if ((unsigned)yy < 32u && (unsigned)xx < 32u)
            vb = *(const bh8*)(xb + (size_t)(yy * 32 + xx) * 1024 + kt + co);
        } else {
          int s = mbase + row, y = s >> 5, x = s & 31;
          int yy = y + dy, xx = x + dx;
          va = zero8;
          if ((unsigned)yy < 32u && (unsigned)xx < 32u)
            va = *(const bh8*)(xb + (size_t)(yy * 32 + xx) * 1024 + kt + co);
          vb = *(const bh8*)(wpt + (size_t)(nbase + row) * 1024 + kt + co);
        }
        *(bh8*)&sA[row][co] = va;
        *(bh8*)&sB[row][co] = vb;
      }
      __syncthreads();
      bh8 af[4], bfr[4];
#pragma unroll
      for (int mt = 0; mt < 4; ++mt)
        af[mt] = *(const bh8*)&sA[wm + mt * 16 + (lane & 15)][(lane >> 4) * 8];
#pragma unroll
      for (int nt = 0; nt < 4; ++nt)
        bfr[nt] = *(const bh8*)&sB[wn + nt * 16 + (lane & 15)][(lane >> 4) * 8];
#pragma unroll
      for (int mt = 0; mt < 4; ++mt)
#pragma unroll
        for (int nt = 0; nt < 4; ++nt)
          acc[mt][nt] = __builtin_amdgcn_mfma_f32_16x16x32_bf16(af[mt], bfr[nt], acc[mt][nt], 0, 0, 0);
      __syncthreads();
    }
  }
  size_t ob = (size_t)b * 1048576;
#pragma unroll
  for (int mt = 0; mt < 4; ++mt) {
#pragma unroll
    for (int nt = 0; nt < 4; ++nt) {
      int m0 = mbase + wm + mt * 16 + ((lane >> 4) << 2);
      int n = nbase + wn + nt * 16 + (lane & 15);
#pragma unroll
      for (int r = 0; r < 4; ++r) {
        float bv = bias[XisA ? n : (m0 + r)];
        out[ob + (size_t)(m0 + r) * 1024 + n] = f2bf(acc[mt][nt][r] + bv);
      }
    }
  }
}

// ---------------------------------------------------------------------------
// Attention per (qtile of 64 t-rows, head, b).  grid (16,16,8), 256 thr.
// Computes S^T tiles (m=s_tok, n=t); two-pass online softmax; P.V.
// Qc,Kc: [b][tok][spatial], VT: [b][spatial][tok], AO: [b][t][h*64+j]
// ---------------------------------------------------------------------------
__global__ __launch_bounds__(256) void attn(
    const short* __restrict__ Qc, const short* __restrict__ Kc,
    const short* __restrict__ VT, const int* __restrict__ mask,
    short* __restrict__ AO) {
  __shared__ short sQ[64][72];
  __shared__ short sK[128][72];
  __shared__ short sV[64][136];
  __shared__ short sP[64][136];
  int tid = threadIdx.x, lane = tid & 63, w = tid >> 6;
  int qbase = blockIdx.x * 64, h = blockIdx.y, b = blockIdx.z;
  int j0 = h * 64;
  const short* Qb = Qc + (size_t)b * 1048576;
  const short* Kb = Kc + (size_t)b * 1048576;
  const short* Vb = VT + (size_t)b * 1048576;
  const int* Mb = mask + (size_t)b * 1048576;
  const float scale = 0.125f;  // 1/sqrt(64)

#pragma unroll
  for (int i = 0; i < 2; ++i) {
    int cid = tid + i * 256;
    int row = cid >> 3, co = (cid & 7) * 8;
    *(bh8*)&sQ[row][co] = *(const bh8*)(Qb + (size_t)(qbase + row) * 1024 + j0 + co);
  }
  __syncthreads();

  int tg = qbase + w * 16 + (lane & 15);  // the t row this lane's stats cover
  float mrow = -3.0e38f, lrow = 0.0f;

  // ---- pass A: softmax stats over all 1024 s ----
  for (int st = 0; st < 8; ++st) {
#pragma unroll
    for (int i = 0; i < 4; ++i) {
      int cid = tid + i * 256;
      int row = cid >> 3, co = (cid & 7) * 8;
      *(bh8*)&sK[row][co] = *(const bh8*)(Kb + (size_t)(st * 128 + row) * 1024 + j0 + co);
    }
    __syncthreads();
    f32x4 sacc[8];
#pragma unroll
    for (int mt = 0; mt < 8; ++mt) {
      f32x4 a = {0.f, 0.f, 0.f, 0.f};
      bh8 kf = *(const bh8*)&sK[mt * 16 + (lane & 15)][(lane >> 4) * 8];
      bh8 qf = *(const bh8*)&sQ[w * 16 + (lane & 15)][(lane >> 4) * 8];
      a = __builtin_amdgcn_mfma_f32_16x16x32_bf16(kf, qf, a, 0, 0, 0);
      kf = *(const bh8*)&sK[mt * 16 + (lane & 15)][32 + (lane >> 4) * 8];
      qf = *(const bh8*)&sQ[w * 16 + (lane & 15)][32 + (lane >> 4) * 8];
      a = __builtin_amdgcn_mfma_f32_16x16x32_bf16(kf, qf, a, 0, 0, 0);
      sacc[mt] = a;
    }
    float tmax = -3.0e38f;
#pragma unroll
    for (int mt = 0; mt < 8; ++mt) {
      int sb = st * 128 + mt * 16 + ((lane >> 4) << 2);
      int4 mi = *(const int4*)(Mb + (size_t)tg * 1024 + sb);
      f32x4 vv;
      vv[0] = mi.x ? sacc[mt][0] * scale : -1e9f;
      vv[1] = mi.y ? sacc[mt][1] * scale : -1e9f;
      vv[2] = mi.z ? sacc[mt][2] * scale : -1e9f;
      vv[3] = mi.w ? sacc[mt][3] * scale : -1e9f;
      sacc[mt] = vv;
      tmax = fmaxf(tmax, fmaxf(fmaxf(vv[0], vv[1]), fmaxf(vv[2], vv[3])));
    }
    tmax = fmaxf(tmax, __shfl_xor(tmax, 16, 64));
    tmax = fmaxf(tmax, __shfl_xor(tmax, 32, 64));
    float mnew = fmaxf(mrow, tmax);
    float sum = 0.f;
#pragma unroll
    for (int mt = 0; mt < 8; ++mt)
#pragma unroll
      for (int r = 0; r < 4; ++r) sum += __expf(fminf(sacc[mt][r] - mnew, 0.f));
    sum += __shfl_xor(sum, 16, 64);
    sum += __shfl_xor(sum, 32, 64);
    lrow = lrow * __expf(fminf(mrow - mnew, 0.f)) + sum;
    mrow = mnew;
    __syncthreads();
  }
  float rl = 1.0f / lrow;

  // ---- pass B: P = exp(S-m)/l, O += P.V ----
  f32x4 oacc[4] = {};
  for (int st = 0; st < 8; ++st) {
#pragma unroll
    for (int i = 0; i < 4; ++i) {
      int cid = tid + i * 256;
      int row = cid >> 3, co = (cid & 7) * 8;
      *(bh8*)&sK[row][co] = *(const bh8*)(Kb + (size_t)(st * 128 + row) * 1024 + j0 + co);
      int vrow = cid >> 4, vco = (cid & 15) * 8;
      *(bh8*)&sV[vrow][vco] = *(const bh8*)(Vb + (size_t)(j0 + vrow) * 1024 + st * 128 + vco);
    }
    __syncthreads();
#pragma unroll
    for (int mt = 0; mt < 8; ++mt) {
      f32x4 a = {0.f, 0.f, 0.f, 0.f};
      bh8 kf = *(const bh8*)&sK[mt * 16 + (lane & 15)][(lane >> 4) * 8];
      bh8 qf = *(const bh8*)&sQ[w * 16 + (lane & 15)][(lane >> 4) * 8];
      a = __builtin_amdgcn_mfma_f32_16x16x32_bf16(kf, qf, a, 0, 0, 0);
      kf = *(const bh8*)&sK[mt * 16 + (lane & 15)][32 + (lane >> 4) * 8];
      qf = *(const bh8*)&sQ[w * 16 + (lane & 15)][32 + (lane >> 4) * 8];
      a = __builtin_amdgcn_mfma_f32_16x16x32_bf16(kf, qf, a, 0, 0, 0);
      int sb = mt * 16 + ((lane >> 4) << 2);
      int4 mi = *(const int4*)(Mb + (size_t)tg * 1024 + st * 128 + sb);
      bh4 p;
      p[0] = mi.x ? f2bf(__expf(fminf(a[0] * scale - mrow, 0.f)) * rl) : (short)0;
      p[1] = mi.y ? f2bf(__expf(fminf(a[1] * scale - mrow, 0.f)) * rl) : (short)0;
      p[2] = mi.z ? f2bf(__expf(fminf(a[2] * scale - mrow, 0.f)) * rl) : (short)0;
      p[3] = mi.w ? f2bf(__expf(fminf(a[3] * scale - mrow, 0.f)) * rl) : (short)0;
      *(bh4*)&sP[w * 16 + (lane & 15)][sb] = p;
    }
    __syncthreads();
#pragma unroll
    for (int k0 = 0; k0 < 4; ++k0) {
      bh8 pf = *(const bh8*)&sP[w * 16 + (lane & 15)][k0 * 32 + (lane >> 4) * 8];
#pragma unroll
      for (int nt = 0; nt < 4; ++nt) {
        bh8 vf = *(const bh8*)&sV[nt * 16 + (lane & 15)][k0 * 32 + (lane >> 4) * 8];
        oacc[nt] = __builtin_amdgcn_mfma_f32_16x16x32_bf16(pf, vf, oacc[nt], 0, 0, 0);
      }
    }
    __syncthreads();
  }
  size_t ob = (size_t)b * 1048576;
#pragma unroll
  for (int nt = 0; nt < 4; ++nt) {
    int j = nt * 16 + (lane & 15);
    int t0 = qbase + w * 16 + ((lane >> 4) << 2);
#pragma unroll
    for (int r = 0; r < 4; ++r)
      AO[ob + (size_t)(t0 + r) * 1024 + j0 + j] = f2bf(oacc[nt][r]);
  }
}

// ---------------------------------------------------------------------------
// Final projection: out[r][o] = sum_m A[r][m] * Wo[o][m] + bo[o]   (f32 out)
// A: [8192][1024] bf16, WoB: [1024][1024] bf16.  grid (64, 8)
// ---------------------------------------------------------------------------
__global__ __launch_bounds__(256) void gemm_bt(
    const short* __restrict__ A, const short* __restrict__ Bm,
    float* __restrict__ out, const float* __restrict__ bias) {
  __shared__ short sA[128][32];
  __shared__ short sB[128][32];
  int tid = threadIdx.x, lane = tid & 63, wid = tid >> 6;
  int mbase = blockIdx.x * 128, nbase = blockIdx.y * 128;
  f32x4 acc[4][4] = {};
  int wm = (wid >> 1) * 64, wn = (wid & 1) * 64;
  for (int kt = 0; kt < 1024; kt += 32) {
#pragma unroll
    for (int i = 0; i < 2; ++i) {
      int cid = tid + i * 256;
      int row = cid >> 2, co = (cid & 3) * 8;
      *(bh8*)&sA[row][co] = *(const bh8*)(A + (size_t)(mbase + row) * 1024 + kt + co);
      *(bh8*)&sB[row][co] = *(const bh8*)(Bm + (size_t)(nbase + row) * 1024 + kt + co);
    }
    __syncthreads();
    bh8 af[4], bfr[4];
#pragma unroll
    for (int mt = 0; mt < 4; ++mt)
      af[mt] = *(const bh8*)&sA[wm + mt * 16 + (lane & 15)][(lane >> 4) * 8];
#pragma unroll
    for (int nt = 0; nt < 4; ++nt)
      bfr[nt] = *(const bh8*)&sB[wn + nt * 16 + (lane & 15)][(lane >> 4) * 8];
#pragma unroll
    for (int mt = 0; mt < 4; ++mt)
#pragma unroll
      for (int nt = 0; nt < 4; ++nt)
        acc[mt][nt] = __builtin_amdgcn_mfma_f32_16x16x32_bf16(af[mt], bfr[nt], acc[mt][nt], 0, 0, 0);
    __syncthreads();
  }
#pragma unroll
  for (int mt = 0; mt < 4; ++mt) {
#pragma unroll
    for (int nt = 0; nt < 4; ++nt) {
      int m0 = mbase + wm + mt * 16 + ((lane >> 4) << 2);
      int n = nbase + wn + nt * 16 + (lane & 15);
      float bv = bias[n];
#pragma unroll
      for (int r = 0; r < 4; ++r)
        out[(size_t)(m0 + r) * 1024 + n] = acc[mt][nt][r] + bv;
    }
  }
}

// ---------------------------------------------------------------------------
extern "C" void kernel_launch(void* const* d_in, const int* in_sizes, int n_in,
                              void* d_out, int out_size, void* d_ws, size_t ws_size,
                              hipStream_t stream) {
  (void)in_sizes; (void)n_in; (void)out_size; (void)ws_size;
  const float* q    = (const float*)d_in[0];
  const float* k    = (const float*)d_in[1];
  const float* v    = (const float*)d_in[2];
  const float* Wq   = (const float*)d_in[3];
  const float* bq   = (const float*)d_in[4];
  const float* Wk   = (const float*)d_in[5];
  const float* bk   = (const float*)d_in[6];
  const float* Wv   = (const float*)d_in[7];
  const float* bv   = (const float*)d_in[8];
  const float* Wo   = (const float*)d_in[9];
  const float* bo   = (const float*)d_in[10];
  const int*   mask = (const int*)d_in[11];
  float* out = (float*)d_out;
  char* ws = (char*)d_ws;

  const size_t MB = 1048576;
  short* qT  = (short*)(ws);                 // 16MB
  short* kT  = (short*)(ws + 16 * MB);       // 16MB
  short* vT  = (short*)(ws + 32 * MB);       // 16MB
  short* WpQ = (short*)(ws + 48 * MB);       // 18MB
  short* WpK = (short*)(ws + 66 * MB);       // 18MB
  short* WpV = (short*)(ws + 84 * MB);       // 18MB
  short* cQ  = (short*)(ws + 102 * MB);      // 16MB
  short* WoB = (short*)(ws + 118 * MB);      // 2MB
  short* cK  = qT;   // qT dead after conv Q
  short* cVT = kT;   // kT dead after conv K
  short* AO  = vT;   // vT dead after conv V    (high-water: 120MB)

  transpose3<<<dim3(16, 16, 24), dim3(256), 0, stream>>>(q, k, v, qT, kT, vT);
  wperm3<<<dim3(4096, 3), dim3(256), 0, stream>>>(Wq, Wk, Wv, WpQ, WpK, WpV);
  cvt_bf<<<dim3(1024), dim3(256), 0, stream>>>(Wo, WoB);
  conv_gemm<0><<<dim3(8, 8, 8), dim3(256), 0, stream>>>(WpQ, qT, cQ, bq);
  conv_gemm<0><<<dim3(8, 8, 8), dim3(256), 0, stream>>>(WpK, kT, cK, bk);
  conv_gemm<1><<<dim3(8, 8, 8), dim3(256), 0, stream>>>(WpV, vT, cVT, bv);
  attn<<<dim3(16, 16, 8), dim3(256), 0, stream>>>(cQ, cK, cVT, mask, AO);
  gemm_bt<<<dim3(64, 8), dim3(256), 0, stream>>>(AO, WoB, out, bo);
}